// Round 12
// baseline (2712.848 us; speedup 1.0000x reference)
//
#include <hip/hip_runtime.h>

#define CH 64
typedef unsigned int uint;
typedef unsigned short ushort;

typedef __attribute__((ext_vector_type(8))) short bf16x8;
typedef __attribute__((ext_vector_type(4))) float f32x4;

// ---------- bf16 helpers ----------
__device__ __forceinline__ float bf_lo(uint u){ union{uint a;float f;}c; c.a=u<<16; return c.f; }
__device__ __forceinline__ float bf_hi(uint u){ union{uint a;float f;}c; c.a=u&0xffff0000u; return c.f; }
__device__ __forceinline__ ushort f2bf(float f){
    uint a = __float_as_uint(f);
    a = (a + 0x7fffu + ((a>>16)&1u)) >> 16;
    return (ushort)a;
}
__device__ __forceinline__ uint pack2(float lo, float hi){
    return (uint)f2bf(lo) | ((uint)f2bf(hi) << 16);
}

// ---------- CSR segment-sum pipeline (replaces atomic scatter) ----------
struct GJob {
    const void* A; const void* B;
    const int* dst; const int* ia; const int* ib;
    uint* S;            // job's S region (rows x 32 uints, bf16x2)
    int* cnt;           // job's count region (int, E entries)
    const int* offs;    // job's exclusive-scan offsets (absolute slot index)
    int* cursor;        // job's fill cursor (preloaded = offs)
    int T; int abf; int bbf;
};
struct GJobs { GJob j[3]; int E; };

// histogram: cnt[dst]++ (3M small atomics)
__global__ __launch_bounds__(256) void hist3(GJobs G)
{
    const int nbj = gridDim.x / 3;
    int job = blockIdx.x / nbj; if (job > 2) job = 2;
    const int nb = (job == 2) ? (gridDim.x - 2*nbj) : nbj;
    const int bj = blockIdx.x - job * nbj;
    const GJob J = G.j[job];
    for (int t = bj*256 + threadIdx.x; t < J.T; t += nb*256)
        atomicAdd(&J.cnt[J.dst[t]], 1);
}

// exclusive scan over packed counts (n up to 3M): 3 passes
#define SCHUNK 2048
__global__ __launch_bounds__(256) void scan_a(const int* __restrict__ cnt, int n, int* __restrict__ bsum)
{
    __shared__ int l[256];
    const int tid = threadIdx.x;
    const int base = blockIdx.x * SCHUNK + tid * 8;
    int s = 0;
    #pragma unroll
    for (int i = 0; i < 8; ++i) { const int idx = base + i; s += (idx < n) ? cnt[idx] : 0; }
    l[tid] = s; __syncthreads();
    if (tid == 0) { int tot = 0; for (int i = 0; i < 256; ++i) tot += l[i]; bsum[blockIdx.x] = tot; }
}
__global__ __launch_bounds__(256) void scan_b(int* __restrict__ bsum, int nb)
{
    __shared__ int l[256];
    const int tid = threadIdx.x;
    const int chunk = (nb + 255) / 256;
    const int lo = tid * chunk, hi = (tid+1)*chunk < nb ? (tid+1)*chunk : nb;
    int s = 0;
    for (int i = lo; i < hi; ++i) s += bsum[i];
    l[tid] = s; __syncthreads();
    if (tid == 0) { int run = 0; for (int i = 0; i < 256; ++i) { int v = l[i]; l[i] = run; run += v; } }
    __syncthreads();
    int run = l[tid];
    for (int i = lo; i < hi; ++i) { int v = bsum[i]; bsum[i] = run; run += v; }
}
__global__ __launch_bounds__(256) void scan_c(const int* __restrict__ cnt, int n,
                                              const int* __restrict__ bsum, int* __restrict__ offs)
{
    __shared__ int l[256];
    const int tid = threadIdx.x;
    const int base = blockIdx.x * SCHUNK + tid * 8;
    int v[8]; int s = 0;
    #pragma unroll
    for (int i = 0; i < 8; ++i) { const int idx = base + i; v[i] = (idx < n) ? cnt[idx] : 0; s += v[i]; }
    l[tid] = s; __syncthreads();
    if (tid == 0) { int run = 0; for (int i = 0; i < 256; ++i) { int x = l[i]; l[i] = run; run += x; } }
    __syncthreads();
    int run = bsum[blockIdx.x] + l[tid];
    #pragma unroll
    for (int i = 0; i < 8; ++i) { const int idx = base + i; if (idx < n) offs[idx] = run; run += v[i]; }
}

// fill CSR: csr[atomicAdd(cursor[dst])] = t
__global__ __launch_bounds__(256) void fill3(GJobs G, int* __restrict__ csr)
{
    const int nbj = gridDim.x / 3;
    int job = blockIdx.x / nbj; if (job > 2) job = 2;
    const int nb = (job == 2) ? (gridDim.x - 2*nbj) : nbj;
    const int bj = blockIdx.x - job * nbj;
    const GJob J = G.j[job];
    for (int t = bj*256 + threadIdx.x; t < J.T; t += nb*256) {
        const int d = J.dst[t];
        const int pos = atomicAdd(&J.cursor[d], 1);
        csr[pos] = t;
    }
}

// gather-accumulate: half-wave per row; fp32 accum; ONE plain bf16 row store.
// NOTE: scalars (cnt/offs/csr/ia/ib) are loaded per-lane — uniform within the
// 32-lane half-wave, so the memory system broadcast-coalesces them. Do NOT use
// readfirstlane here: it reads lane 0 of the FULL 64-lane wave, which would
// feed the upper half-wave the lower half-wave's row data (R11 bug).
__global__ __launch_bounds__(256) void gather3(GJobs G, const int* __restrict__ csr)
{
    const int nbj = gridDim.x / 3;
    int job = blockIdx.x / nbj; if (job > 2) job = 2;
    const int nb = (job == 2) ? (gridDim.x - 2*nbj) : nbj;
    const int bj = blockIdx.x - job * nbj;
    const GJob J = G.j[job];
    const int l32 = threadIdx.x & 31;
    const int hw  = ((bj << 8) + threadIdx.x) >> 5;
    const int nhw = (nb << 8) >> 5;
    const bool abf = J.abf != 0, bbf = J.bbf != 0;
    const int E = G.E;

    for (int r = hw; r < E; r += nhw) {
        const int n    = J.cnt[r];
        const int base = J.offs[r];
        float a0 = 0.f, a1 = 0.f;
        for (int k = 0; k < n; ++k) {
            const int t  = csr[base + k];
            const int ia = J.ia[t];
            const int ib = J.ib[t];
            if (abf) { const uint u = ((const uint*)J.A)[(size_t)ia*32 + l32]; a0 += bf_lo(u); a1 += bf_hi(u); }
            else     { const float2 f = ((const float2*)J.A)[(size_t)ia*32 + l32]; a0 += f.x; a1 += f.y; }
            if (bbf) { const uint u = ((const uint*)J.B)[(size_t)ib*32 + l32]; a0 += bf_lo(u); a1 += bf_hi(u); }
            else     { const float2 f = ((const float2*)J.B)[(size_t)ib*32 + l32]; a0 += f.x; a1 += f.y; }
        }
        J.S[(size_t)r*32 + l32] = pack2(a0, a1);
    }
}

// ---------- fp32 -> packed bf16 row copies ----------
__global__ __launch_bounds__(256) void conv_bf16_kernel(
    const float* __restrict__ src, uint* __restrict__ dst, long n4)
{
    long i = (long)blockIdx.x * blockDim.x + threadIdx.x;
    const long stride = (long)gridDim.x * blockDim.x;
    for (; i < n4; i += stride) {
        const float4 v = ((const float4*)src)[i];
        uint2 o; o.x = pack2(v.x, v.y); o.y = pack2(v.z, v.w);
        ((uint2*)dst)[i] = o;
    }
}

// ---------- MFMA fused finalize (R4 structure: measured local optimum) ----
// out[r] = mlp( base[r] + SA@WA + cA*bA + SB@WB + cB*bB
//               + (SC[r]+SC[inv])@WC + (cC[r]+cC[inv])*bC )
// Block = 256 thr = 4 waves, 64 rows/block (16 rows/wave).
__global__ __launch_bounds__(256) void fused_finalize_mfma(
    const float* __restrict__ base,
    const uint* __restrict__ SA, const int* __restrict__ cA,
    const float* __restrict__ WA, const float* __restrict__ bA,
    const uint* __restrict__ SB, const int* __restrict__ cB,
    const float* __restrict__ WB, const float* __restrict__ bB,
    const uint* __restrict__ SC, const int* __restrict__ cC,
    const float* __restrict__ WC, const float* __restrict__ bC,
    const int* __restrict__ inv,
    const float* __restrict__ W1, const float* __restrict__ b1,
    const float* __restrict__ W2, const float* __restrict__ b2,
    int N, float* __restrict__ out, uint* __restrict__ out_bf)
{
    __shared__ __attribute__((aligned(16))) char lds[49152]; // 5*8KB W + 4*2KB z
    const int tid = threadIdx.x;

    // ---- stage 5 weight matrices (fp32 [k][col] -> bf16 W^T, swizzled) ----
    const float* Wlist[5] = {WA, WB, WC, W1, W2};
    #pragma unroll
    for (int m = 0; m < 5; ++m) {
        const float* Wm = Wlist[m];
        for (int idx = tid; idx < 4096; idx += 256) {
            const int k = idx >> 6, col = idx & 63;       // coalesced global read
            *(ushort*)(lds + m*8192 + col*128 + ((2*k) ^ ((col&7)<<4))) = f2bf(Wm[idx]);
        }
    }
    __syncthreads();

    const int w = tid >> 6, lane = tid & 63;
    const int ln = lane & 15, grp = lane >> 4;
    const int r0 = blockIdx.x * 64 + w * 16;
    const int ra = (r0 + ln) < N ? (r0 + ln) : (N - 1);   // A-frag row (clamped)
    const int iva = inv[ra];
    char* zl = lds + 40960 + w * 2048;                    // per-wave 16x64 bf16

    auto ldS = [&](const uint* Srow, int kc) {
        union { uint4 u; bf16x8 h; } c;
        c.u = *(const uint4*)(Srow + kc*16 + grp*4);
        return c.h;
    };
    auto ldS2 = [&](const uint* r1, const uint* r2, int kc) {
        const uint4 a = *(const uint4*)(r1 + kc*16 + grp*4);
        const uint4 b = *(const uint4*)(r2 + kc*16 + grp*4);
        union { uint4 u; bf16x8 h; } c;
        c.u.x = pack2(bf_lo(a.x)+bf_lo(b.x), bf_hi(a.x)+bf_hi(b.x));
        c.u.y = pack2(bf_lo(a.y)+bf_lo(b.y), bf_hi(a.y)+bf_hi(b.y));
        c.u.z = pack2(bf_lo(a.z)+bf_lo(b.z), bf_hi(a.z)+bf_hi(b.z));
        c.u.w = pack2(bf_lo(a.w)+bf_lo(b.w), bf_hi(a.w)+bf_hi(b.w));
        return c.h;
    };
    auto ldW = [&](int m, int kc, int ct) {
        const int col = ct*16 + ln;
        const int k2  = (kc*32 + grp*8) * 2;
        return *(const bf16x8*)(lds + m*8192 + col*128 + (k2 ^ ((col&7)<<4)));
    };
    auto ldZ = [&](int kc) {
        const int k2 = (kc*32 + grp*8) * 2;
        return *(const bf16x8*)(zl + ln*128 + (k2 ^ ((ln&7)<<4)));
    };
    auto stZ = [&](int row, int col, float v) {
        *(ushort*)(zl + row*128 + ((2*col) ^ ((row&7)<<4))) = f2bf(v);
    };

    const uint* SArow  = SA + (size_t)ra * 32;
    const uint* SBrow  = SB + (size_t)ra * 32;
    const uint* SCrow  = SC + (size_t)ra * 32;
    const uint* SCrow2 = SC + (size_t)iva * 32;

    const f32x4 z4 = {0.f, 0.f, 0.f, 0.f};
    f32x4 acc[4] = {z4, z4, z4, z4};

    // ---- z = SA@WA + SB@WB + (SC+SCinv)@WC  (K=64 each, 2 chunks of 32) ----
    #pragma unroll
    for (int kc = 0; kc < 2; ++kc) {
        const bf16x8 aA = ldS(SArow, kc);
        const bf16x8 aB = ldS(SBrow, kc);
        const bf16x8 aC = ldS2(SCrow, SCrow2, kc);
        #pragma unroll
        for (int ct = 0; ct < 4; ++ct) {
            acc[ct] = __builtin_amdgcn_mfma_f32_16x16x32_bf16(aA, ldW(0,kc,ct), acc[ct], 0,0,0);
            acc[ct] = __builtin_amdgcn_mfma_f32_16x16x32_bf16(aB, ldW(1,kc,ct), acc[ct], 0,0,0);
            acc[ct] = __builtin_amdgcn_mfma_f32_16x16x32_bf16(aC, ldW(2,kc,ct), acc[ct], 0,0,0);
        }
    }

    // ---- fp32 epilogue: + base + counts*bias; write z to zl as bf16 ----
    #pragma unroll
    for (int reg = 0; reg < 4; ++reg) {
        const int rd = r0 + grp*4 + reg;
        const int rc = rd < N ? rd : (N - 1);
        const float fA = (float)cA[rc], fB = (float)cB[rc];
        const float fC = (float)(cC[rc] + cC[inv[rc]]);
        #pragma unroll
        for (int ct = 0; ct < 4; ++ct) {
            const int col = ct*16 + ln;
            acc[ct][reg] += base[(size_t)rc*64 + col] + fA*bA[col] + fB*bB[col] + fC*bC[col];
        }
    }
    #pragma unroll
    for (int ct = 0; ct < 4; ++ct)
        #pragma unroll
        for (int reg = 0; reg < 4; ++reg)
            stZ(grp*4 + reg, ct*16 + ln, acc[ct][reg]);
    // zl is wave-private; DS ops within a wave are in-order -> no barrier.

    // ---- MLP layer 1: h = relu(z @ W1 + b1) ----
    f32x4 hacc[4] = {z4, z4, z4, z4};
    #pragma unroll
    for (int kc = 0; kc < 2; ++kc) {
        const bf16x8 az = ldZ(kc);
        #pragma unroll
        for (int ct = 0; ct < 4; ++ct)
            hacc[ct] = __builtin_amdgcn_mfma_f32_16x16x32_bf16(az, ldW(3,kc,ct), hacc[ct], 0,0,0);
    }
    #pragma unroll
    for (int ct = 0; ct < 4; ++ct)
        #pragma unroll
        for (int reg = 0; reg < 4; ++reg)
            stZ(grp*4 + reg, ct*16 + ln, fmaxf(hacc[ct][reg] + b1[ct*16 + ln], 0.f));

    // ---- MLP layer 2: out = h @ W2 + b2 ----
    f32x4 oacc[4] = {z4, z4, z4, z4};
    #pragma unroll
    for (int kc = 0; kc < 2; ++kc) {
        const bf16x8 ah = ldZ(kc);
        #pragma unroll
        for (int ct = 0; ct < 4; ++ct)
            oacc[ct] = __builtin_amdgcn_mfma_f32_16x16x32_bf16(ah, ldW(4,kc,ct), oacc[ct], 0,0,0);
    }
    #pragma unroll
    for (int reg = 0; reg < 4; ++reg) {
        const int rd = r0 + grp*4 + reg;
        if (rd < N) {
            #pragma unroll
            for (int ct = 0; ct < 4; ++ct) {
                const int col = ct*16 + ln;
                const float o = oacc[ct][reg] + b2[col];
                out[(size_t)rd*64 + col] = o;
                if (out_bf) ((ushort*)out_bf)[(size_t)rd*64 + col] = f2bf(o);
            }
        }
    }
}

extern "C" void kernel_launch(void* const* d_in, const int* in_sizes, int n_in,
                              void* d_out, int out_size, void* d_ws, size_t ws_size,
                              hipStream_t stream)
{
    const float* ea  = (const float*)d_in[0];
    const float* ea2 = (const float*)d_in[1];
    const float* Wp  = (const float*)d_in[2];   // (6,64,64)
    const float* bp  = (const float*)d_in[3];   // (6,64)
    const float* W1a = (const float*)d_in[4];
    const float* b1a = (const float*)d_in[5];
    const float* W2a = (const float*)d_in[6];
    const float* b2a = (const float*)d_in[7];
    const float* W1b = (const float*)d_in[8];
    const float* b1b = (const float*)d_in[9];
    const float* W2b = (const float*)d_in[10];
    const float* b2b = (const float*)d_in[11];
    const int* t111 = (const int*)d_in[12];     // [3,T]: ij, ik, kj
    const int* t112 = (const int*)d_in[13];
    const int* t122 = (const int*)d_in[14];
    const int* t222 = (const int*)d_in[15];
    const int* inv1 = (const int*)d_in[16];
    const int* inv2 = (const int*)d_in[17];

    const int E    = in_sizes[0] / CH;
    const int E2   = in_sizes[1] / CH;
    const int T111 = in_sizes[12] / 3;
    const int T112 = in_sizes[13] / 3;
    const int T122 = in_sizes[14] / 3;
    const int T222 = in_sizes[15] / 3;

    float* out1 = (float*)d_out;
    float* out2 = out1 + (size_t)E * CH;

    const size_t R = (size_t)(E > E2 ? E : E2);
    const int Tsum1 = T111 + T122 + T112;
    const int Tsum2 = T112 + T222 + T122;
    const int Tcap  = Tsum1 > Tsum2 ? Tsum1 : Tsum2;

    char* p = (char*)d_ws;
    uint*  Sbase  = (uint*)p;  p += 3 * R * 128;
    int*   cntI   = (int*)p;   p += 3 * R * 4;
    int*   offs   = (int*)p;   p += 3 * R * 4;
    int*   cursor = (int*)p;   p += 3 * R * 4;
    int*   csr    = (int*)p;   p += (size_t)Tcap * 4;
    int*   bsum   = (int*)p;   p += 8192 * 4;
    size_t used = (size_t)(p - (char*)d_ws);
    uint* ea2_bf = nullptr;
    uint* out1_bf = nullptr;
    uint* ea_bf  = nullptr;
    if (ws_size >= used + (size_t)E2 * 128) { ea2_bf = (uint*)p; p += (size_t)E2 * 128; used += (size_t)E2 * 128; }
    if (ws_size >= used + (size_t)E  * 128) { out1_bf = (uint*)p; p += (size_t)E * 128; used += (size_t)E * 128; }
    if (ws_size >= used + (size_t)E  * 128) { ea_bf  = (uint*)p; }

    const dim3 blk256(256);
    const int NB3 = 3072;     // 1024 blocks/job

    if (ea2_bf) conv_bf16_kernel<<<2048, blk256, 0, stream>>>(ea2, ea2_bf, (long)E2 * 16);
    if (ea_bf)  conv_bf16_kernel<<<2048, blk256, 0, stream>>>(ea,  ea_bf,  (long)E  * 16);

    const void* eaS  = ea_bf  ? (const void*)ea_bf  : (const void*)ea;
    const void* ea2S = ea2_bf ? (const void*)ea2_bf : (const void*)ea2;
    const int eaB = ea_bf != nullptr, ea2B = ea2_bf != nullptr;

    auto run_phase = [&](GJobs& G, int Eph) {
        const int n3 = 3 * Eph;
        const int nbs = (n3 + SCHUNK - 1) / SCHUNK;
        hipMemsetAsync(cntI, 0, (size_t)n3 * 4, stream);
        hist3<<<NB3, blk256, 0, stream>>>(G);
        scan_a<<<nbs, blk256, 0, stream>>>(cntI, n3, bsum);
        scan_b<<<1,   blk256, 0, stream>>>(bsum, nbs);
        scan_c<<<nbs, blk256, 0, stream>>>(cntI, n3, bsum, offs);
        hipMemcpyAsync(cursor, offs, (size_t)n3 * 4, hipMemcpyDeviceToDevice, stream);
        fill3<<<NB3, blk256, 0, stream>>>(G, csr);
        gather3<<<NB3, blk256, 0, stream>>>(G, csr);
    };

    // ================= Phase 1 (edges1) =================
    uint*  SA1 = Sbase;           uint*  SB1 = Sbase + (size_t)E*32;  uint*  SC1 = Sbase + (size_t)2*E*32;
    {
        GJobs G; G.E = E;
        // SA1: ea[ik111]+ea[kj111] seg ij111   (-> Wp0)
        G.j[0] = {eaS,  eaS,  t111 + 0, t111 + T111, t111 + 2*T111, SA1, cntI,       offs,       cursor,       T111, eaB,  eaB};
        // SB1: ea2[ik122]+ea2[kj122] seg ij122 (-> Wp2)
        G.j[1] = {ea2S, ea2S, t122 + 0, t122 + T122, t122 + 2*T122, SB1, cntI + E,   offs + E,   cursor + E,   T122, ea2B, ea2B};
        // SC1: ea[ik112]+ea2[kj112] seg ij112  (-> Wp1, doubled via inv1)
        G.j[2] = {eaS,  ea2S, t112 + 0, t112 + T112, t112 + 2*T112, SC1, cntI + 2*E, offs + 2*E, cursor + 2*E, T112, eaB,  ea2B};
        run_phase(G, E);
    }

    fused_finalize_mfma<<<(E + 63) / 64, blk256, 0, stream>>>(
        ea,
        SA1, cntI,       Wp + 0*CH*CH, bp + 0*CH,
        SB1, cntI + E,   Wp + 2*CH*CH, bp + 2*CH,
        SC1, cntI + 2*E, Wp + 1*CH*CH, bp + 1*CH,
        inv1, W1a, b1a, W2a, b2a, E, out1, out1_bf);

    // ================= Phase 2 (edges2) =================
    uint*  SA2 = Sbase;           uint*  SB2 = Sbase + (size_t)E2*32; uint*  SC2 = Sbase + (size_t)2*E2*32;
    const void* o1S = out1_bf ? (const void*)out1_bf : (const void*)out1;
    const int o1B = out1_bf != nullptr;
    {
        GJobs G; G.E = E2;
        // SA2: out1[ij112]+out1[ik112] seg kj112 (-> Wp3)
        G.j[0] = {o1S,  o1S,  t112 + 2*T112, t112 + 0,    t112 + T112,   SA2, cntI,        offs,        cursor,        T112, o1B,  o1B};
        // SB2: ea2[ik222]+ea2[kj222] seg ij222   (-> Wp5)
        G.j[1] = {ea2S, ea2S, t222 + 0,      t222 + T222, t222 + 2*T222, SB2, cntI + E2,   offs + E2,   cursor + E2,   T222, ea2B, ea2B};
        // SC2: out1[ij122]+ea2[kj122] seg ik122   (-> Wp4, doubled via inv2)
        G.j[2] = {o1S,  ea2S, t122 + T122,   t122 + 0,    t122 + 2*T122, SC2, cntI + 2*E2, offs + 2*E2, cursor + 2*E2, T122, o1B,  ea2B};
        run_phase(G, E2);
    }

    fused_finalize_mfma<<<(E2 + 63) / 64, blk256, 0, stream>>>(
        ea2,
        SA2, cntI,        Wp + 3*CH*CH, bp + 3*CH,
        SB2, cntI + E2,   Wp + 5*CH*CH, bp + 5*CH,
        SC2, cntI + 2*E2, Wp + 4*CH*CH, bp + 4*CH,
        inv2, W1b, b1b, W2b, b2b, E2, out2, nullptr);
}